// Round 9
// baseline (3317.434 us; speedup 1.0000x reference)
//
#include <hip/hip_runtime.h>
#include <math.h>

// 3-layer LSTM (H=64, D=300, B=256, T=512) + MLP head (64 -> tanh 64 -> 300).
// R7e: byte-identical resubmission of R7 (four consecutive infra failures;
// the launch_bounds fix has never executed). Fix under test: R6's scan spill.
// Root cause (measured R4): w[4][64] = 256 VGPRs + ~70 live regs exceeded the
// compiler's default 256-reg budget -> scratch spill (VALUBusy 11.5%,
// 220us/dispatch, VGPR_Count pinned at 256). Fix: __launch_bounds__(64, 1)
// -> min 1 wave/EU -> up to 512 VGPRs/wave on gfx950 unified file.
// Architecture unchanged: one-wave-per-row barrier-free scan, in-lane gate
// combine, same-wave LDS h exchange, gate-interleaved xp from MFMA
// split-product GEMMs.

#define TT 512
#define BB 256
#define DD 300
#define HH 64
#define MM (TT * BB)
#define XP 256            // 4H
#define TC 128            // time chunk
#define NC (TT / TC)

typedef __attribute__((ext_vector_type(8))) short bf16x8;
typedef __attribute__((ext_vector_type(4))) float f32x4;

__device__ __forceinline__ float bf2f(unsigned short u) {
    return __uint_as_float(((unsigned int)u) << 16);
}
__device__ __forceinline__ unsigned short f2bf(float f) {
    unsigned int x = __float_as_uint(f);
    x += 0x7FFFu + ((x >> 16) & 1u);   // RNE
    return (unsigned short)(x >> 16);
}
__device__ __forceinline__ float tanh_f(float x) { return 1.f - 2.f / (__expf(2.f * x) + 1.f); }

// dual-mode loads: md==1 -> fp32 buffer, md==0 -> bf16 buffer
__device__ __forceinline__ float ld1(const void* p, long long i, int md) {
    return md ? ((const float*)p)[i] : bf2f(((const unsigned short*)p)[i]);
}
__device__ __forceinline__ void ld4v(float* d, const void* p, long long i, int md) {
    if (md) {
        float4 v = *(const float4*)((const float*)p + i);
        d[0] = v.x; d[1] = v.y; d[2] = v.z; d[3] = v.w;
    } else {
        ushort4 u = *(const ushort4*)((const unsigned short*)p + i);
        d[0] = bf2f(u.x); d[1] = bf2f(u.y); d[2] = bf2f(u.z); d[3] = bf2f(u.w);
    }
}

__device__ __forceinline__ f32x4 mfma16(bf16x8 a, bf16x8 b, f32x4 c) {
    return __builtin_amdgcn_mfma_f32_16x16x32_bf16(a, b, c, 0, 0, 0);
}

// 6-term split product: (a1+a2+a3)*(b1+b2+b3), dropping terms < 2^-24
__device__ __forceinline__ f32x4 mfma6(bf16x8 a1, bf16x8 a2, bf16x8 a3,
                                       bf16x8 b1, bf16x8 b2, bf16x8 b3, f32x4 t) {
    t = mfma16(a2, b2, t);
    t = mfma16(a1, b3, t);
    t = mfma16(a3, b1, t);
    t = mfma16(a1, b2, t);
    t = mfma16(a2, b1, t);
    t = mfma16(a1, b1, t);
    return t;
}

// 3-way bf16 split of 4 floats
__device__ __forceinline__ void split3x4(const float* v, ushort4& h1, ushort4& h2, ushort4& h3) {
    unsigned short a[4], b[4], c[4];
    #pragma unroll
    for (int e = 0; e < 4; ++e) {
        unsigned short x = f2bf(v[e]);
        float r1 = v[e] - bf2f(x);
        unsigned short y = f2bf(r1);
        float r2 = r1 - bf2f(y);
        unsigned short z = f2bf(r2);
        a[e] = x; b[e] = y; c[e] = z;
    }
    h1 = make_ushort4(a[0], a[1], a[2], a[3]);
    h2 = make_ushort4(b[0], b[1], b[2], b[3]);
    h3 = make_ushort4(c[0], c[1], c[2], c[3]);
}

// ---------------------------------------------------------------------------
__global__ void detect_kernel(const void* inp, int* mode) {
    if (threadIdx.x == 0 && blockIdx.x == 0) {
        const unsigned short* u = (const unsigned short*)inp;
        int bad = 0;
        for (int i = 0; i < 256; ++i) {
            float f = bf2f(u[i]);
            if (!(f == f) || fabsf(f) > 1e6f) ++bad;
        }
        *mode = (bad >= 4) ? 1 : 0;
    }
}

__global__ __launch_bounds__(256) void init_state(
    const void* h0, const void* c0, float* hstate, float* cstate, const int* modep)
{
    const int md = *modep;
    int i = blockIdx.x * 256 + threadIdx.x;
    if (i < 3 * BB * HH) {
        hstate[i] = ld1(h0, i, md);
        cstate[i] = ld1(c0, i, md);
    }
}

__global__ __launch_bounds__(256) void final_state(
    const float* hstate, const float* cstate, void* out, const int* modep)
{
    const int md = *modep;
    int i = blockIdx.x * 256 + threadIdx.x;
    const long long base = (long long)MM * DD;
    if (i < 3 * BB * HH) {
        if (md) {
            ((float*)out)[base + i] = hstate[i];
            ((float*)out)[base + 3 * BB * HH + i] = cstate[i];
        } else {
            ((unsigned short*)out)[base + i] = f2bf(hstate[i]);
            ((unsigned short*)out)[base + 3 * BB * HH + i] = f2bf(cstate[i]);
        }
    }
}

// ---------------------------------------------------------------------------
// split_w: pre-split a weight tensor into 3 bf16 planes [rdst][cdst] (padded
// with zeros beyond rsrc/csrc). dst layout: [hi | mid | lo], each rdst*cdst.
// ---------------------------------------------------------------------------
__global__ __launch_bounds__(256) void split_w(
    const void* __restrict__ src, unsigned short* __restrict__ dst,
    int rsrc, int csrc, int rdst, int cdst, const int* modep)
{
    const int md = *modep;
    int i = blockIdx.x * 256 + threadIdx.x;
    int n = rdst * cdst;
    if (i >= n) return;
    int r = i / cdst, cc = i - r * cdst;
    float v = (r < rsrc && cc < csrc) ? ld1(src, (long long)r * csrc + cc, md) : 0.f;
    unsigned short a = f2bf(v);
    float r1 = v - bf2f(a);
    unsigned short b = f2bf(r1);
    float r2 = r1 - bf2f(b);
    unsigned short c = f2bf(r2);
    dst[i] = a; dst[n + i] = b; dst[2 * n + i] = c;
}

// ---------------------------------------------------------------------------
// proj0_chunk: xp'[ml][4*(n&63)+(n>>6)] = sum_k input(b,t,k)*wih0[n][k] + bias
// grid 512, blk 256. MFMA split-product. W pre-split planes [256][320].
// ---------------------------------------------------------------------------
__global__ __launch_bounds__(256, 2) void proj0_chunk(
    const void* __restrict__ inp, const unsigned short* __restrict__ wsp,
    const void* __restrict__ bih, const void* __restrict__ bhh,
    float* __restrict__ xp, const int* modep, int chunk)
{
    const int md = *modep;
    __shared__ __align__(16) unsigned short aS[3][64 * 40];
    __shared__ __align__(16) unsigned short wS[3][256 * 40];
    const int tid = threadIdx.x;
    const int m0 = blockIdx.x * 64;
    const int lane = tid & 63, wv = tid >> 6;
    const int fr = lane & 15, fq = lane >> 4;
    const int ar = tid >> 2, acs = (tid & 3) * 8;
    const int ml = m0 + ar;
    const int b = ml & 255;
    const int t = chunk * TC + (ml >> 8);
    const long long abase = (long long)b * (TT * DD) + (long long)t * DD;
    float bias[4];
    #pragma unroll
    for (int nf = 0; nf < 4; ++nf) {
        int n = wv * 64 + nf * 16 + fr;
        bias[nf] = ld1(bih, n, md) + ld1(bhh, n, md);
    }
    f32x4 acc[4][4] = {};
    for (int p = 0; p < 10; ++p) {
        const int k0 = p * 32;
        // stage A (row ar, 8 cols at acs), 3-way split
        #pragma unroll
        for (int q = 0; q < 2; ++q) {
            const int kg = k0 + acs + q * 4;
            float v[4];
            if (kg + 3 < DD) {
                ld4v(v, inp, abase + kg, md);
            } else {
                #pragma unroll
                for (int e = 0; e < 4; ++e)
                    v[e] = (kg + e < DD) ? ld1(inp, abase + kg + e, md) : 0.f;
            }
            ushort4 h1, h2, h3;
            split3x4(v, h1, h2, h3);
            *(ushort4*)(&aS[0][ar * 40 + acs + q * 4]) = h1;
            *(ushort4*)(&aS[1][ar * 40 + acs + q * 4]) = h2;
            *(ushort4*)(&aS[2][ar * 40 + acs + q * 4]) = h3;
        }
        // stage W: row tid, 32 cols, 3 pre-split planes (pure copies)
        #pragma unroll
        for (int pl = 0; pl < 3; ++pl) {
            const uint4* gw = (const uint4*)(wsp + (size_t)pl * 81920 + (size_t)tid * 320 + k0);
            uint4* dw = (uint4*)(&wS[pl][tid * 40]);
            #pragma unroll
            for (int qq = 0; qq < 4; ++qq) dw[qq] = gw[qq];
        }
        __syncthreads();
        bf16x8 wf[4][3];
        #pragma unroll
        for (int nf = 0; nf < 4; ++nf) {
            #pragma unroll
            for (int pl = 0; pl < 3; ++pl)
                wf[nf][pl] = *(const bf16x8*)(&wS[pl][(wv * 64 + nf * 16 + fr) * 40 + fq * 8]);
        }
        #pragma unroll
        for (int mf = 0; mf < 4; ++mf) {
            bf16x8 a1 = *(const bf16x8*)(&aS[0][(mf * 16 + fr) * 40 + fq * 8]);
            bf16x8 a2 = *(const bf16x8*)(&aS[1][(mf * 16 + fr) * 40 + fq * 8]);
            bf16x8 a3 = *(const bf16x8*)(&aS[2][(mf * 16 + fr) * 40 + fq * 8]);
            #pragma unroll
            for (int nf = 0; nf < 4; ++nf)
                acc[mf][nf] = mfma6(a1, a2, a3, wf[nf][0], wf[nf][1], wf[nf][2], acc[mf][nf]);
        }
        __syncthreads();
    }
    // C/D layout: col = lane&15, row = (lane>>4)*4 + reg; write gate-interleaved
    #pragma unroll
    for (int mf = 0; mf < 4; ++mf) {
        #pragma unroll
        for (int nf = 0; nf < 4; ++nf) {
            const int colp = ((nf * 16 + fr) << 2) | wv;
            #pragma unroll
            for (int r = 0; r < 4; ++r) {
                const int row = m0 + mf * 16 + fq * 4 + r;
                xp[(long long)row * XP + colp] = acc[mf][nf][r] + bias[nf];
            }
        }
    }
}

// ---------------------------------------------------------------------------
// projh_chunk: xp'[m][4*(n&63)+(n>>6)] = sum_k A[m][k]*wih[n][k] + bias
// A fp32 [TC*BB][64]. W pre-split planes [256][64].
// ---------------------------------------------------------------------------
__global__ __launch_bounds__(256, 2) void projh_chunk(
    const float* __restrict__ A, const unsigned short* __restrict__ wsp,
    const void* __restrict__ bih, const void* __restrict__ bhh,
    float* __restrict__ xp, const int* modep)
{
    const int md = *modep;
    __shared__ __align__(16) unsigned short aS[3][64 * 40];
    __shared__ __align__(16) unsigned short wS[3][256 * 40];
    const int tid = threadIdx.x;
    const int m0 = blockIdx.x * 64;
    const int lane = tid & 63, wv = tid >> 6;
    const int fr = lane & 15, fq = lane >> 4;
    const int ar = tid >> 2, acs = (tid & 3) * 8;
    float bias[4];
    #pragma unroll
    for (int nf = 0; nf < 4; ++nf) {
        int n = wv * 64 + nf * 16 + fr;
        bias[nf] = ld1(bih, n, md) + ld1(bhh, n, md);
    }
    f32x4 acc[4][4] = {};
    #pragma unroll
    for (int p = 0; p < 2; ++p) {
        const int k0 = p * 32;
        #pragma unroll
        for (int q = 0; q < 2; ++q) {
            float v[4];
            const float4 fv = *(const float4*)(A + (long long)(m0 + ar) * HH + k0 + acs + q * 4);
            v[0] = fv.x; v[1] = fv.y; v[2] = fv.z; v[3] = fv.w;
            ushort4 h1, h2, h3;
            split3x4(v, h1, h2, h3);
            *(ushort4*)(&aS[0][ar * 40 + acs + q * 4]) = h1;
            *(ushort4*)(&aS[1][ar * 40 + acs + q * 4]) = h2;
            *(ushort4*)(&aS[2][ar * 40 + acs + q * 4]) = h3;
        }
        #pragma unroll
        for (int pl = 0; pl < 3; ++pl) {
            const uint4* gw = (const uint4*)(wsp + (size_t)pl * 16384 + (size_t)tid * 64 + k0);
            uint4* dw = (uint4*)(&wS[pl][tid * 40]);
            #pragma unroll
            for (int qq = 0; qq < 4; ++qq) dw[qq] = gw[qq];
        }
        __syncthreads();
        bf16x8 wf[4][3];
        #pragma unroll
        for (int nf = 0; nf < 4; ++nf) {
            #pragma unroll
            for (int pl = 0; pl < 3; ++pl)
                wf[nf][pl] = *(const bf16x8*)(&wS[pl][(wv * 64 + nf * 16 + fr) * 40 + fq * 8]);
        }
        #pragma unroll
        for (int mf = 0; mf < 4; ++mf) {
            bf16x8 a1 = *(const bf16x8*)(&aS[0][(mf * 16 + fr) * 40 + fq * 8]);
            bf16x8 a2 = *(const bf16x8*)(&aS[1][(mf * 16 + fr) * 40 + fq * 8]);
            bf16x8 a3 = *(const bf16x8*)(&aS[2][(mf * 16 + fr) * 40 + fq * 8]);
            #pragma unroll
            for (int nf = 0; nf < 4; ++nf)
                acc[mf][nf] = mfma6(a1, a2, a3, wf[nf][0], wf[nf][1], wf[nf][2], acc[mf][nf]);
        }
        __syncthreads();
    }
    #pragma unroll
    for (int mf = 0; mf < 4; ++mf) {
        #pragma unroll
        for (int nf = 0; nf < 4; ++nf) {
            const int colp = ((nf * 16 + fr) << 2) | wv;
            #pragma unroll
            for (int r = 0; r < 4; ++r) {
                const int row = m0 + mf * 16 + fq * 4 + r;
                xp[(long long)row * XP + colp] = acc[mf][nf][r] + bias[nf];
            }
        }
    }
}

// ---------------------------------------------------------------------------
// scan_chunk: ONE WAVE per batch row. Lane i owns h-index i and computes all
// 4 gate rows {i, 64+i, 128+i, 192+i}. No barriers, no shfl: gate combine is
// in-lane; h exchange via same-wave LDS (per-wave in-order DS pipe).
// Weights in VGPRs: w[4][64] = 256 regs. launch_bounds(64, 1) -> min 1
// wave/EU -> up to 512 VGPRs/wave (R6's 256-cap caused the spill regression).
// xp is gate-interleaved: float4 at col 4*i = {i,f,g,o} pre-activations.
// ---------------------------------------------------------------------------
__global__ __launch_bounds__(64, 1) void scan_chunk(
    const float* __restrict__ xp, float* __restrict__ hs,
    const void* __restrict__ whh,
    float* __restrict__ hstate, float* __restrict__ cstate, const int* modep)
{
    const int md = *modep;
    const int b = blockIdx.x;
    const int i = threadIdx.x;      // 0..63, h-index
    __shared__ __align__(16) float h_s[2][64];
    float w[4][64];
    #pragma unroll
    for (int tau = 0; tau < 4; ++tau) {
        const long long base = (long long)(tau * 64 + i) * HH;
        #pragma unroll
        for (int q = 0; q < 16; ++q) {
            float v[4];
            ld4v(v, whh, base + q * 4, md);
            w[tau][4*q+0] = v[0]; w[tau][4*q+1] = v[1];
            w[tau][4*q+2] = v[2]; w[tau][4*q+3] = v[3];
        }
    }
    float c = cstate[b * HH + i];
    h_s[0][i] = hstate[b * HH + i];
    float hval = 0.f;

    const long long xbase = (long long)b * XP + 4 * i;
    const long long xstep = (long long)BB * XP;
    float4 xc[4], xn[4];
    #pragma unroll
    for (int p = 0; p < 4; ++p)
        xc[p] = *(const float4*)(xp + xbase + (long long)p * xstep);

    for (int tg = 0; tg < TC; tg += 4) {
        if (tg + 4 < TC) {
            #pragma unroll
            for (int p = 0; p < 4; ++p)
                xn[p] = *(const float4*)(xp + xbase + (long long)(tg + 4 + p) * xstep);
        }
        #pragma unroll
        for (int u = 0; u < 4; ++u) {
            const int t = tg + u;
            // 4 gate dots over h (shared h loads, 16 fma chains)
            float a0[4], a1[4], a2[4], a3[4];
            a0[0] = xc[u].x; a0[1] = xc[u].y; a0[2] = xc[u].z; a0[3] = xc[u].w;
            #pragma unroll
            for (int tau = 0; tau < 4; ++tau) { a1[tau] = 0.f; a2[tau] = 0.f; a3[tau] = 0.f; }
            asm volatile("" ::: "memory");   // compiler fence: no hoist of h reads
            const float4* h4 = (const float4*)h_s[t & 1];
            #pragma unroll
            for (int q = 0; q < 16; ++q) {
                float4 hv = h4[q];
                #pragma unroll
                for (int tau = 0; tau < 4; ++tau) {
                    a0[tau] = fmaf(hv.x, w[tau][4*q+0], a0[tau]);
                    a1[tau] = fmaf(hv.y, w[tau][4*q+1], a1[tau]);
                    a2[tau] = fmaf(hv.z, w[tau][4*q+2], a2[tau]);
                    a3[tau] = fmaf(hv.w, w[tau][4*q+3], a3[tau]);
                }
            }
            float y[4];
            #pragma unroll
            for (int tau = 0; tau < 4; ++tau) {
                float gr = (a0[tau] + a1[tau]) + (a2[tau] + a3[tau]);
                const float aa = (tau == 2) ? 2.f : 1.f;   // tanh(x)=2*sig(2x)-1
                const float cc = 1.f - aa;
                float s = 1.f / (1.f + __expf(-aa * gr));
                y[tau] = fmaf(aa, s, cc);
            }
            c = y[1] * c + y[0] * y[2];
            hval = y[3] * tanh_f(c);
            h_s[(t & 1) ^ 1][i] = hval;
            asm volatile("" ::: "memory");   // commit h write before next step
            hs[((long long)t * BB + b) * HH + i] = hval;
        }
        #pragma unroll
        for (int p = 0; p < 4; ++p) xc[p] = xn[p];
    }
    hstate[b * HH + i] = hval;
    cstate[b * HH + i] = c;
}

// ---------------------------------------------------------------------------
// head_chunk: y = tanh(hs2 @ w1^T + b1) @ w2^T + b2, MFMA split-product.
// w1 planes [64][64], w2 planes [320][64] (rows>=300 zero).
// ---------------------------------------------------------------------------
__global__ __launch_bounds__(256, 1) void head_chunk(
    const float* __restrict__ hs, const unsigned short* __restrict__ w1p,
    const void* __restrict__ b1, const unsigned short* __restrict__ w2p,
    const void* __restrict__ b2, void* __restrict__ out,
    const int* modep, int chunk)
{
    const int md = *modep;
    __shared__ __align__(16) unsigned short aS[3][64 * 72];
    __shared__ __align__(16) unsigned short wS[3][64 * 72];
    __shared__ __align__(16) unsigned short zS[3][64 * 72];
    const int tid = threadIdx.x;
    const int m0 = blockIdx.x * 64;
    const long long gbase = (long long)chunk * TC * BB;
    const int lane = tid & 63, wv = tid >> 6;
    const int fr = lane & 15, fq = lane >> 4;
    const int ar = tid >> 2, cs = (tid & 3) * 16;
    // stage A = hs tile (3-way split) and w1 planes (copy)
    #pragma unroll
    for (int e = 0; e < 4; ++e) {
        float v[4];
        const float4 fv = *(const float4*)(hs + (long long)(m0 + ar) * HH + cs + e * 4);
        v[0] = fv.x; v[1] = fv.y; v[2] = fv.z; v[3] = fv.w;
        ushort4 h1, h2, h3;
        split3x4(v, h1, h2, h3);
        *(ushort4*)(&aS[0][ar * 72 + cs + e * 4]) = h1;
        *(ushort4*)(&aS[1][ar * 72 + cs + e * 4]) = h2;
        *(ushort4*)(&aS[2][ar * 72 + cs + e * 4]) = h3;
    }
    #pragma unroll
    for (int pl = 0; pl < 3; ++pl) {
        const uint4* g1 = (const uint4*)(w1p + (size_t)pl * 4096 + (size_t)ar * 64 + cs);
        *(uint4*)(&wS[pl][ar * 72 + cs]) = g1[0];
        *(uint4*)(&wS[pl][ar * 72 + cs + 8]) = g1[1];
    }
    __syncthreads();
    // phase 1: Z = tanh(A @ w1^T + b1); wave wv owns m-rows [wv*16, +16)
    {
        bf16x8 af[2][3];
        #pragma unroll
        for (int kf = 0; kf < 2; ++kf) {
            #pragma unroll
            for (int pl = 0; pl < 3; ++pl)
                af[kf][pl] = *(const bf16x8*)(&aS[pl][(wv * 16 + fr) * 72 + kf * 32 + fq * 8]);
        }
        f32x4 acc1[4] = {};
        #pragma unroll
        for (int nf = 0; nf < 4; ++nf) {
            #pragma unroll
            for (int kf = 0; kf < 2; ++kf) {
                bf16x8 b1f = *(const bf16x8*)(&wS[0][(nf * 16 + fr) * 72 + kf * 32 + fq * 8]);
                bf16x8 b2f = *(const bf16x8*)(&wS[1][(nf * 16 + fr) * 72 + kf * 32 + fq * 8]);
                bf16x8 b3f = *(const bf16x8*)(&wS[2][(nf * 16 + fr) * 72 + kf * 32 + fq * 8]);
                acc1[nf] = mfma6(af[kf][0], af[kf][1], af[kf][2], b1f, b2f, b3f, acc1[nf]);
            }
        }
        #pragma unroll
        for (int nf = 0; nf < 4; ++nf) {
            float bb = ld1(b1, nf * 16 + fr, md);
            #pragma unroll
            for (int r = 0; r < 4; ++r) {
                float z = tanh_f(acc1[nf][r] + bb);
                unsigned short zh = f2bf(z);
                float r1 = z - bf2f(zh);
                unsigned short zm = f2bf(r1);
                float r2 = r1 - bf2f(zm);
                unsigned short zl = f2bf(r2);
                int zi = (wv * 16 + fq * 4 + r) * 72 + nf * 16 + fr;
                zS[0][zi] = zh; zS[1][zi] = zm; zS[2][zi] = zl;
            }
        }
    }
    __syncthreads();
    // hoist Z fragments (stable across dt loop)
    bf16x8 zf[2][3];
    #pragma unroll
    for (int kf = 0; kf < 2; ++kf) {
        #pragma unroll
        for (int pl = 0; pl < 3; ++pl)
            zf[kf][pl] = *(const bf16x8*)(&zS[pl][(wv * 16 + fr) * 72 + kf * 32 + fq * 8]);
    }
    // phase 2: out = Z @ w2^T + b2, N=300 in 5 chunks of 64
    for (int dt = 0; dt < 5; ++dt) {
        #pragma unroll
        for (int pl = 0; pl < 3; ++pl) {
            const uint4* g2 = (const uint4*)(w2p + (size_t)pl * 20480 + (size_t)(dt * 64 + ar) * 64 + cs);
            *(uint4*)(&wS[pl][ar * 72 + cs]) = g2[0];
            *(uint4*)(&wS[pl][ar * 72 + cs + 8]) = g2[1];
        }
        __syncthreads();
        f32x4 acc[4] = {};
        #pragma unroll
        for (int nf = 0; nf < 4; ++nf) {
            #pragma unroll
            for (int kf = 0; kf < 2; ++kf) {
                bf16x8 b1f = *(const bf16x8*)(&wS[0][(nf * 16 + fr) * 72 + kf * 32 + fq * 8]);
                bf16x8 b2f = *(const bf16x8*)(&wS[1][(nf * 16 + fr) * 72 + kf * 32 + fq * 8]);
                bf16x8 b3f = *(const bf16x8*)(&wS[2][(nf * 16 + fr) * 72 + kf * 32 + fq * 8]);
                acc[nf] = mfma6(zf[kf][0], zf[kf][1], zf[kf][2], b1f, b2f, b3f, acc[nf]);
            }
        }
        #pragma unroll
        for (int nf = 0; nf < 4; ++nf) {
            const int col = dt * 64 + nf * 16 + fr;
            if (col < DD) {
                float bb = ld1(b2, col, md);
                #pragma unroll
                for (int r = 0; r < 4; ++r) {
                    long long row = gbase + m0 + wv * 16 + fq * 4 + r;
                    float o = acc[nf][r] + bb;
                    if (md) ((float*)out)[row * DD + col] = o;
                    else    ((unsigned short*)out)[row * DD + col] = f2bf(o);
                }
            }
        }
        __syncthreads();
    }
}

// ---------------------------------------------------------------------------
extern "C" void kernel_launch(void* const* d_in, const int* in_sizes, int n_in,
                              void* d_out, int out_size, void* d_ws, size_t ws_size,
                              hipStream_t stream)
{
    const void* inp  = d_in[0];
    const void* h0   = d_in[1];
    const void* c0   = d_in[2];
    const void* wih0 = d_in[3];
    const void* whh0 = d_in[4];
    const void* bih0 = d_in[5];
    const void* bhh0 = d_in[6];
    const void* wih1 = d_in[7];
    const void* whh1 = d_in[8];
    const void* bih1 = d_in[9];
    const void* bhh1 = d_in[10];
    const void* wih2 = d_in[11];
    const void* whh2 = d_in[12];
    const void* bih2 = d_in[13];
    const void* bhh2 = d_in[14];
    const void* w1   = d_in[15];
    const void* b1   = d_in[16];
    const void* w2   = d_in[17];
    const void* b2   = d_in[18];

    int* mode = (int*)d_ws;
    float* wsf = (float*)d_ws;
    float* hstate = wsf + 16;                          // [3,256,64]
    float* cstate = hstate + 3 * BB * HH;
    float* xp  = cstate + 3 * BB * HH;                 // [TC*256, 256]
    float* hs  = xp + (size_t)TC * BB * XP;            // [TC*256, 64] (reused per layer)
    unsigned short* w0s = (unsigned short*)(hs + (size_t)TC * BB * HH);
    unsigned short* w1s = w0s + (size_t)3 * 81920;     // [3][256*320]
    unsigned short* w2s = w1s + (size_t)3 * 16384;     // [3][256*64]
    unsigned short* h1s = w2s + (size_t)3 * 16384;     // [3][256*64]
    unsigned short* h2s = h1s + (size_t)3 * 4096;      // [3][64*64]
                                                       // h2s: [3][320*64]

    detect_kernel<<<1, 64, 0, stream>>>(inp, mode);
    init_state<<<192, 256, 0, stream>>>(h0, c0, hstate, cstate, mode);
    split_w<<<320, 256, 0, stream>>>(wih0, w0s, 256, 300, 256, 320, mode);
    split_w<<<64, 256, 0, stream>>>(wih1, w1s, 256, 64, 256, 64, mode);
    split_w<<<64, 256, 0, stream>>>(wih2, w2s, 256, 64, 256, 64, mode);
    split_w<<<16, 256, 0, stream>>>(w1, h1s, 64, 64, 64, 64, mode);
    split_w<<<80, 256, 0, stream>>>(w2, h2s, 300, 64, 320, 64, mode);

    for (int c = 0; c < NC; ++c) {
        proj0_chunk<<<dim3(TC * BB / 64), 256, 0, stream>>>(
            inp, w0s, bih0, bhh0, xp, mode, c);
        scan_chunk<<<BB, 64, 0, stream>>>(
            xp, hs, whh0, hstate, cstate, mode);
        projh_chunk<<<dim3(TC * BB / 64), 256, 0, stream>>>(
            hs, w1s, bih1, bhh1, xp, mode);
        scan_chunk<<<BB, 64, 0, stream>>>(
            xp, hs, whh1, hstate + BB * HH, cstate + BB * HH, mode);
        projh_chunk<<<dim3(TC * BB / 64), 256, 0, stream>>>(
            hs, w2s, bih2, bhh2, xp, mode);
        scan_chunk<<<BB, 64, 0, stream>>>(
            xp, hs, whh2, hstate + 2 * BB * HH, cstate + 2 * BB * HH, mode);
        head_chunk<<<TC * BB / 64, 256, 0, stream>>>(
            hs, h1s, b1, h2s, b2, d_out, mode, c);
    }
    final_state<<<192, 256, 0, stream>>>(hstate, cstate, d_out, mode);
}

// Round 10
// 1909.332 us; speedup vs baseline: 1.7375x; 1.7375x over previous
//
#include <hip/hip_runtime.h>
#include <math.h>

// 3-layer LSTM (H=64, D=300, B=256, T=512) + MLP head (64 -> tanh 64 -> 300).
// R8: two-wave scan. R9's measurement falsified the launch_bounds theory:
// VGPR_Count stays pinned at 256 (architectural arch-VGPR ceiling: VALU
// operand encoding addresses v0-v255; the 512 "unified" pool's upper half is
// AGPRs). One-wave w[4][64]=256 weight VGPRs can never fit. Redesign:
// 2 waves/row, wave0 owns gates {i,f}, wave1 owns {g,o} -> w[2][64]=128 weight
// VGPRs (~190 total, no spill). One LDS float2 exchange + one s_barrier per
// step (2-wave skew); both waves redundantly compute c/h (same-value LDS race
// is benign; in-wave DS ordering covers each wave's own h_s read).
// Gate dot arithmetic chain-identical to R2/R4 -> absmax unchanged.
// GEMMs (MFMA 3-way-split, gate-interleaved xp) unchanged.

#define TT 512
#define BB 256
#define DD 300
#define HH 64
#define MM (TT * BB)
#define XP 256            // 4H
#define TC 128            // time chunk
#define NC (TT / TC)

typedef __attribute__((ext_vector_type(8))) short bf16x8;
typedef __attribute__((ext_vector_type(4))) float f32x4;

__device__ __forceinline__ float bf2f(unsigned short u) {
    return __uint_as_float(((unsigned int)u) << 16);
}
__device__ __forceinline__ unsigned short f2bf(float f) {
    unsigned int x = __float_as_uint(f);
    x += 0x7FFFu + ((x >> 16) & 1u);   // RNE
    return (unsigned short)(x >> 16);
}
__device__ __forceinline__ float tanh_f(float x) { return 1.f - 2.f / (__expf(2.f * x) + 1.f); }

// dual-mode loads: md==1 -> fp32 buffer, md==0 -> bf16 buffer
__device__ __forceinline__ float ld1(const void* p, long long i, int md) {
    return md ? ((const float*)p)[i] : bf2f(((const unsigned short*)p)[i]);
}
__device__ __forceinline__ void ld4v(float* d, const void* p, long long i, int md) {
    if (md) {
        float4 v = *(const float4*)((const float*)p + i);
        d[0] = v.x; d[1] = v.y; d[2] = v.z; d[3] = v.w;
    } else {
        ushort4 u = *(const ushort4*)((const unsigned short*)p + i);
        d[0] = bf2f(u.x); d[1] = bf2f(u.y); d[2] = bf2f(u.z); d[3] = bf2f(u.w);
    }
}

__device__ __forceinline__ f32x4 mfma16(bf16x8 a, bf16x8 b, f32x4 c) {
    return __builtin_amdgcn_mfma_f32_16x16x32_bf16(a, b, c, 0, 0, 0);
}

// 6-term split product: (a1+a2+a3)*(b1+b2+b3), dropping terms < 2^-24
__device__ __forceinline__ f32x4 mfma6(bf16x8 a1, bf16x8 a2, bf16x8 a3,
                                       bf16x8 b1, bf16x8 b2, bf16x8 b3, f32x4 t) {
    t = mfma16(a2, b2, t);
    t = mfma16(a1, b3, t);
    t = mfma16(a3, b1, t);
    t = mfma16(a1, b2, t);
    t = mfma16(a2, b1, t);
    t = mfma16(a1, b1, t);
    return t;
}

// 3-way bf16 split of 4 floats
__device__ __forceinline__ void split3x4(const float* v, ushort4& h1, ushort4& h2, ushort4& h3) {
    unsigned short a[4], b[4], c[4];
    #pragma unroll
    for (int e = 0; e < 4; ++e) {
        unsigned short x = f2bf(v[e]);
        float r1 = v[e] - bf2f(x);
        unsigned short y = f2bf(r1);
        float r2 = r1 - bf2f(y);
        unsigned short z = f2bf(r2);
        a[e] = x; b[e] = y; c[e] = z;
    }
    h1 = make_ushort4(a[0], a[1], a[2], a[3]);
    h2 = make_ushort4(b[0], b[1], b[2], b[3]);
    h3 = make_ushort4(c[0], c[1], c[2], c[3]);
}

// ---------------------------------------------------------------------------
__global__ void detect_kernel(const void* inp, int* mode) {
    if (threadIdx.x == 0 && blockIdx.x == 0) {
        const unsigned short* u = (const unsigned short*)inp;
        int bad = 0;
        for (int i = 0; i < 256; ++i) {
            float f = bf2f(u[i]);
            if (!(f == f) || fabsf(f) > 1e6f) ++bad;
        }
        *mode = (bad >= 4) ? 1 : 0;
    }
}

__global__ __launch_bounds__(256) void init_state(
    const void* h0, const void* c0, float* hstate, float* cstate, const int* modep)
{
    const int md = *modep;
    int i = blockIdx.x * 256 + threadIdx.x;
    if (i < 3 * BB * HH) {
        hstate[i] = ld1(h0, i, md);
        cstate[i] = ld1(c0, i, md);
    }
}

__global__ __launch_bounds__(256) void final_state(
    const float* hstate, const float* cstate, void* out, const int* modep)
{
    const int md = *modep;
    int i = blockIdx.x * 256 + threadIdx.x;
    const long long base = (long long)MM * DD;
    if (i < 3 * BB * HH) {
        if (md) {
            ((float*)out)[base + i] = hstate[i];
            ((float*)out)[base + 3 * BB * HH + i] = cstate[i];
        } else {
            ((unsigned short*)out)[base + i] = f2bf(hstate[i]);
            ((unsigned short*)out)[base + 3 * BB * HH + i] = f2bf(cstate[i]);
        }
    }
}

// ---------------------------------------------------------------------------
// split_w: pre-split a weight tensor into 3 bf16 planes [rdst][cdst] (padded
// with zeros beyond rsrc/csrc). dst layout: [hi | mid | lo], each rdst*cdst.
// ---------------------------------------------------------------------------
__global__ __launch_bounds__(256) void split_w(
    const void* __restrict__ src, unsigned short* __restrict__ dst,
    int rsrc, int csrc, int rdst, int cdst, const int* modep)
{
    const int md = *modep;
    int i = blockIdx.x * 256 + threadIdx.x;
    int n = rdst * cdst;
    if (i >= n) return;
    int r = i / cdst, cc = i - r * cdst;
    float v = (r < rsrc && cc < csrc) ? ld1(src, (long long)r * csrc + cc, md) : 0.f;
    unsigned short a = f2bf(v);
    float r1 = v - bf2f(a);
    unsigned short b = f2bf(r1);
    float r2 = r1 - bf2f(b);
    unsigned short c = f2bf(r2);
    dst[i] = a; dst[n + i] = b; dst[2 * n + i] = c;
}

// ---------------------------------------------------------------------------
// proj0_chunk: xp'[ml][4*(n&63)+(n>>6)] = sum_k input(b,t,k)*wih0[n][k] + bias
// grid 512, blk 256. MFMA split-product. W pre-split planes [256][320].
// ---------------------------------------------------------------------------
__global__ __launch_bounds__(256, 2) void proj0_chunk(
    const void* __restrict__ inp, const unsigned short* __restrict__ wsp,
    const void* __restrict__ bih, const void* __restrict__ bhh,
    float* __restrict__ xp, const int* modep, int chunk)
{
    const int md = *modep;
    __shared__ __align__(16) unsigned short aS[3][64 * 40];
    __shared__ __align__(16) unsigned short wS[3][256 * 40];
    const int tid = threadIdx.x;
    const int m0 = blockIdx.x * 64;
    const int lane = tid & 63, wv = tid >> 6;
    const int fr = lane & 15, fq = lane >> 4;
    const int ar = tid >> 2, acs = (tid & 3) * 8;
    const int ml = m0 + ar;
    const int b = ml & 255;
    const int t = chunk * TC + (ml >> 8);
    const long long abase = (long long)b * (TT * DD) + (long long)t * DD;
    float bias[4];
    #pragma unroll
    for (int nf = 0; nf < 4; ++nf) {
        int n = wv * 64 + nf * 16 + fr;
        bias[nf] = ld1(bih, n, md) + ld1(bhh, n, md);
    }
    f32x4 acc[4][4] = {};
    for (int p = 0; p < 10; ++p) {
        const int k0 = p * 32;
        // stage A (row ar, 8 cols at acs), 3-way split
        #pragma unroll
        for (int q = 0; q < 2; ++q) {
            const int kg = k0 + acs + q * 4;
            float v[4];
            if (kg + 3 < DD) {
                ld4v(v, inp, abase + kg, md);
            } else {
                #pragma unroll
                for (int e = 0; e < 4; ++e)
                    v[e] = (kg + e < DD) ? ld1(inp, abase + kg + e, md) : 0.f;
            }
            ushort4 h1, h2, h3;
            split3x4(v, h1, h2, h3);
            *(ushort4*)(&aS[0][ar * 40 + acs + q * 4]) = h1;
            *(ushort4*)(&aS[1][ar * 40 + acs + q * 4]) = h2;
            *(ushort4*)(&aS[2][ar * 40 + acs + q * 4]) = h3;
        }
        // stage W: row tid, 32 cols, 3 pre-split planes (pure copies)
        #pragma unroll
        for (int pl = 0; pl < 3; ++pl) {
            const uint4* gw = (const uint4*)(wsp + (size_t)pl * 81920 + (size_t)tid * 320 + k0);
            uint4* dw = (uint4*)(&wS[pl][tid * 40]);
            #pragma unroll
            for (int qq = 0; qq < 4; ++qq) dw[qq] = gw[qq];
        }
        __syncthreads();
        bf16x8 wf[4][3];
        #pragma unroll
        for (int nf = 0; nf < 4; ++nf) {
            #pragma unroll
            for (int pl = 0; pl < 3; ++pl)
                wf[nf][pl] = *(const bf16x8*)(&wS[pl][(wv * 64 + nf * 16 + fr) * 40 + fq * 8]);
        }
        #pragma unroll
        for (int mf = 0; mf < 4; ++mf) {
            bf16x8 a1 = *(const bf16x8*)(&aS[0][(mf * 16 + fr) * 40 + fq * 8]);
            bf16x8 a2 = *(const bf16x8*)(&aS[1][(mf * 16 + fr) * 40 + fq * 8]);
            bf16x8 a3 = *(const bf16x8*)(&aS[2][(mf * 16 + fr) * 40 + fq * 8]);
            #pragma unroll
            for (int nf = 0; nf < 4; ++nf)
                acc[mf][nf] = mfma6(a1, a2, a3, wf[nf][0], wf[nf][1], wf[nf][2], acc[mf][nf]);
        }
        __syncthreads();
    }
    // C/D layout: col = lane&15, row = (lane>>4)*4 + reg; write gate-interleaved
    #pragma unroll
    for (int mf = 0; mf < 4; ++mf) {
        #pragma unroll
        for (int nf = 0; nf < 4; ++nf) {
            const int colp = ((nf * 16 + fr) << 2) | wv;
            #pragma unroll
            for (int r = 0; r < 4; ++r) {
                const int row = m0 + mf * 16 + fq * 4 + r;
                xp[(long long)row * XP + colp] = acc[mf][nf][r] + bias[nf];
            }
        }
    }
}

// ---------------------------------------------------------------------------
// projh_chunk: xp'[m][4*(n&63)+(n>>6)] = sum_k A[m][k]*wih[n][k] + bias
// A fp32 [TC*BB][64]. W pre-split planes [256][64].
// ---------------------------------------------------------------------------
__global__ __launch_bounds__(256, 2) void projh_chunk(
    const float* __restrict__ A, const unsigned short* __restrict__ wsp,
    const void* __restrict__ bih, const void* __restrict__ bhh,
    float* __restrict__ xp, const int* modep)
{
    const int md = *modep;
    __shared__ __align__(16) unsigned short aS[3][64 * 40];
    __shared__ __align__(16) unsigned short wS[3][256 * 40];
    const int tid = threadIdx.x;
    const int m0 = blockIdx.x * 64;
    const int lane = tid & 63, wv = tid >> 6;
    const int fr = lane & 15, fq = lane >> 4;
    const int ar = tid >> 2, acs = (tid & 3) * 8;
    float bias[4];
    #pragma unroll
    for (int nf = 0; nf < 4; ++nf) {
        int n = wv * 64 + nf * 16 + fr;
        bias[nf] = ld1(bih, n, md) + ld1(bhh, n, md);
    }
    f32x4 acc[4][4] = {};
    #pragma unroll
    for (int p = 0; p < 2; ++p) {
        const int k0 = p * 32;
        #pragma unroll
        for (int q = 0; q < 2; ++q) {
            float v[4];
            const float4 fv = *(const float4*)(A + (long long)(m0 + ar) * HH + k0 + acs + q * 4);
            v[0] = fv.x; v[1] = fv.y; v[2] = fv.z; v[3] = fv.w;
            ushort4 h1, h2, h3;
            split3x4(v, h1, h2, h3);
            *(ushort4*)(&aS[0][ar * 40 + acs + q * 4]) = h1;
            *(ushort4*)(&aS[1][ar * 40 + acs + q * 4]) = h2;
            *(ushort4*)(&aS[2][ar * 40 + acs + q * 4]) = h3;
        }
        #pragma unroll
        for (int pl = 0; pl < 3; ++pl) {
            const uint4* gw = (const uint4*)(wsp + (size_t)pl * 16384 + (size_t)tid * 64 + k0);
            uint4* dw = (uint4*)(&wS[pl][tid * 40]);
            #pragma unroll
            for (int qq = 0; qq < 4; ++qq) dw[qq] = gw[qq];
        }
        __syncthreads();
        bf16x8 wf[4][3];
        #pragma unroll
        for (int nf = 0; nf < 4; ++nf) {
            #pragma unroll
            for (int pl = 0; pl < 3; ++pl)
                wf[nf][pl] = *(const bf16x8*)(&wS[pl][(wv * 64 + nf * 16 + fr) * 40 + fq * 8]);
        }
        #pragma unroll
        for (int mf = 0; mf < 4; ++mf) {
            bf16x8 a1 = *(const bf16x8*)(&aS[0][(mf * 16 + fr) * 40 + fq * 8]);
            bf16x8 a2 = *(const bf16x8*)(&aS[1][(mf * 16 + fr) * 40 + fq * 8]);
            bf16x8 a3 = *(const bf16x8*)(&aS[2][(mf * 16 + fr) * 40 + fq * 8]);
            #pragma unroll
            for (int nf = 0; nf < 4; ++nf)
                acc[mf][nf] = mfma6(a1, a2, a3, wf[nf][0], wf[nf][1], wf[nf][2], acc[mf][nf]);
        }
        __syncthreads();
    }
    #pragma unroll
    for (int mf = 0; mf < 4; ++mf) {
        #pragma unroll
        for (int nf = 0; nf < 4; ++nf) {
            const int colp = ((nf * 16 + fr) << 2) | wv;
            #pragma unroll
            for (int r = 0; r < 4; ++r) {
                const int row = m0 + mf * 16 + fq * 4 + r;
                xp[(long long)row * XP + colp] = acc[mf][nf][r] + bias[nf];
            }
        }
    }
}

// ---------------------------------------------------------------------------
// scan_chunk: TWO WAVES per batch row (128 threads). Wave 0 lane i owns gate
// rows {i, 64+i} (i,f); wave 1 lane i owns {128+i, 192+i} (g,o).
// w[2][64] = 128 weight VGPRs (+~60 live ≈ 190 < 256 arch ceiling; R9 proved
// 256 is a hard cap). Per step: 2 gate dots sharing broadcast h reads; y-pair
// exchanged via LDS float2 + ONE s_barrier (lgkmcnt-only wait, no vmcnt
// drain); both waves redundantly compute c/h (identical bits -> same-value
// LDS race benign; in-wave DS ordering covers own h_s read next step).
// xp gate-interleaved: float2 at col 4*i + 2*wid = this lane's 2 gates.
// ---------------------------------------------------------------------------
__global__ __launch_bounds__(128, 1) void scan_chunk(
    const float* __restrict__ xp, float* __restrict__ hs,
    const void* __restrict__ whh,
    float* __restrict__ hstate, float* __restrict__ cstate, const int* modep)
{
    const int md = *modep;
    const int b = blockIdx.x;
    const int j = threadIdx.x;
    const int wid = j >> 6;          // 0: gates {i,f}; 1: gates {g,o}
    const int i = j & 63;            // h-index
    __shared__ __align__(16) float h_s[2][64];
    __shared__ __align__(16) float2 g2_s[2][2][64];   // [parity][wid][i]
    float w[2][64];
    #pragma unroll
    for (int tt = 0; tt < 2; ++tt) {
        const int tau = wid * 2 + tt;
        const long long base = (long long)(tau * 64 + i) * HH;
        #pragma unroll
        for (int q = 0; q < 16; ++q) {
            float v[4];
            ld4v(v, whh, base + q * 4, md);
            w[tt][4*q+0] = v[0]; w[tt][4*q+1] = v[1];
            w[tt][4*q+2] = v[2]; w[tt][4*q+3] = v[3];
        }
    }
    float c = cstate[b * HH + i];
    h_s[0][i] = hstate[b * HH + i];   // both waves write identical values
    float hval = 0.f;

    const float aa0 = (wid == 1) ? 2.f : 1.f;   // tau=2 (g) is tanh: 2*sig(2x)-1
    const float cc0 = 1.f - aa0;

    const long long xbase = (long long)b * XP + 4 * i + 2 * wid;
    const long long xstep = (long long)BB * XP;
    float2 xc[4], xn[4];
    #pragma unroll
    for (int p = 0; p < 4; ++p)
        xc[p] = *(const float2*)(xp + xbase + (long long)p * xstep);

    for (int tg = 0; tg < TC; tg += 4) {
        if (tg + 4 < TC) {
            #pragma unroll
            for (int p = 0; p < 4; ++p)
                xn[p] = *(const float2*)(xp + xbase + (long long)(tg + 4 + p) * xstep);
        }
        #pragma unroll
        for (int u = 0; u < 4; ++u) {
            const int t = tg + u;
            // 2 gate dots over h (shared broadcast h loads, 4 chains each)
            float a0[2], a1[2], a2[2], a3[2];
            a0[0] = xc[u].x; a0[1] = xc[u].y;
            #pragma unroll
            for (int tt = 0; tt < 2; ++tt) { a1[tt] = 0.f; a2[tt] = 0.f; a3[tt] = 0.f; }
            asm volatile("" ::: "memory");   // no hoist of h reads
            const float4* h4 = (const float4*)h_s[t & 1];
            #pragma unroll
            for (int q = 0; q < 16; ++q) {
                float4 hv = h4[q];
                #pragma unroll
                for (int tt = 0; tt < 2; ++tt) {
                    a0[tt] = fmaf(hv.x, w[tt][4*q+0], a0[tt]);
                    a1[tt] = fmaf(hv.y, w[tt][4*q+1], a1[tt]);
                    a2[tt] = fmaf(hv.z, w[tt][4*q+2], a2[tt]);
                    a3[tt] = fmaf(hv.w, w[tt][4*q+3], a3[tt]);
                }
            }
            float gr0 = (a0[0] + a1[0]) + (a2[0] + a3[0]);
            float gr1 = (a0[1] + a1[1]) + (a2[1] + a3[1]);
            float s0 = 1.f / (1.f + __expf(-aa0 * gr0));
            float y0 = fmaf(aa0, s0, cc0);               // tau even: sig or tanh
            float y1 = 1.f / (1.f + __expf(-gr1));       // tau odd: always sig
            g2_s[t & 1][wid][i] = make_float2(y0, y1);
            // commit LDS, sync both waves; vmcnt NOT drained (prefetch+stores fly)
            asm volatile("s_waitcnt lgkmcnt(0)\n\ts_barrier" ::: "memory");
            float2 pr = g2_s[t & 1][wid ^ 1][i];
            float yi, yf, yg, yo;
            if (wid == 0) { yi = y0;   yf = y1;   yg = pr.x; yo = pr.y; }
            else          { yi = pr.x; yf = pr.y; yg = y0;   yo = y1;   }
            c = yf * c + yi * yg;
            hval = yo * tanh_f(c);
            h_s[(t & 1) ^ 1][i] = hval;   // both waves, identical value
            asm volatile("" ::: "memory");
            if (wid == 0) hs[((long long)t * BB + b) * HH + i] = hval;
        }
        #pragma unroll
        for (int p = 0; p < 4; ++p) xc[p] = xn[p];
    }
    if (wid == 0) {
        hstate[b * HH + i] = hval;
        cstate[b * HH + i] = c;
    }
}

// ---------------------------------------------------------------------------
// head_chunk: y = tanh(hs2 @ w1^T + b1) @ w2^T + b2, MFMA split-product.
// w1 planes [64][64], w2 planes [320][64] (rows>=300 zero).
// ---------------------------------------------------------------------------
__global__ __launch_bounds__(256, 1) void head_chunk(
    const float* __restrict__ hs, const unsigned short* __restrict__ w1p,
    const void* __restrict__ b1, const unsigned short* __restrict__ w2p,
    const void* __restrict__ b2, void* __restrict__ out,
    const int* modep, int chunk)
{
    const int md = *modep;
    __shared__ __align__(16) unsigned short aS[3][64 * 72];
    __shared__ __align__(16) unsigned short wS[3][64 * 72];
    __shared__ __align__(16) unsigned short zS[3][64 * 72];
    const int tid = threadIdx.x;
    const int m0 = blockIdx.x * 64;
    const long long gbase = (long long)chunk * TC * BB;
    const int lane = tid & 63, wv = tid >> 6;
    const int fr = lane & 15, fq = lane >> 4;
    const int ar = tid >> 2, cs = (tid & 3) * 16;
    // stage A = hs tile (3-way split) and w1 planes (copy)
    #pragma unroll
    for (int e = 0; e < 4; ++e) {
        float v[4];
        const float4 fv = *(const float4*)(hs + (long long)(m0 + ar) * HH + cs + e * 4);
        v[0] = fv.x; v[1] = fv.y; v[2] = fv.z; v[3] = fv.w;
        ushort4 h1, h2, h3;
        split3x4(v, h1, h2, h3);
        *(ushort4*)(&aS[0][ar * 72 + cs + e * 4]) = h1;
        *(ushort4*)(&aS[1][ar * 72 + cs + e * 4]) = h2;
        *(ushort4*)(&aS[2][ar * 72 + cs + e * 4]) = h3;
    }
    #pragma unroll
    for (int pl = 0; pl < 3; ++pl) {
        const uint4* g1 = (const uint4*)(w1p + (size_t)pl * 4096 + (size_t)ar * 64 + cs);
        *(uint4*)(&wS[pl][ar * 72 + cs]) = g1[0];
        *(uint4*)(&wS[pl][ar * 72 + cs + 8]) = g1[1];
    }
    __syncthreads();
    // phase 1: Z = tanh(A @ w1^T + b1); wave wv owns m-rows [wv*16, +16)
    {
        bf16x8 af[2][3];
        #pragma unroll
        for (int kf = 0; kf < 2; ++kf) {
            #pragma unroll
            for (int pl = 0; pl < 3; ++pl)
                af[kf][pl] = *(const bf16x8*)(&aS[pl][(wv * 16 + fr) * 72 + kf * 32 + fq * 8]);
        }
        f32x4 acc1[4] = {};
        #pragma unroll
        for (int nf = 0; nf < 4; ++nf) {
            #pragma unroll
            for (int kf = 0; kf < 2; ++kf) {
                bf16x8 b1f = *(const bf16x8*)(&wS[0][(nf * 16 + fr) * 72 + kf * 32 + fq * 8]);
                bf16x8 b2f = *(const bf16x8*)(&wS[1][(nf * 16 + fr) * 72 + kf * 32 + fq * 8]);
                bf16x8 b3f = *(const bf16x8*)(&wS[2][(nf * 16 + fr) * 72 + kf * 32 + fq * 8]);
                acc1[nf] = mfma6(af[kf][0], af[kf][1], af[kf][2], b1f, b2f, b3f, acc1[nf]);
            }
        }
        #pragma unroll
        for (int nf = 0; nf < 4; ++nf) {
            float bb = ld1(b1, nf * 16 + fr, md);
            #pragma unroll
            for (int r = 0; r < 4; ++r) {
                float z = tanh_f(acc1[nf][r] + bb);
                unsigned short zh = f2bf(z);
                float r1 = z - bf2f(zh);
                unsigned short zm = f2bf(r1);
                float r2 = r1 - bf2f(zm);
                unsigned short zl = f2bf(r2);
                int zi = (wv * 16 + fq * 4 + r) * 72 + nf * 16 + fr;
                zS[0][zi] = zh; zS[1][zi] = zm; zS[2][zi] = zl;
            }
        }
    }
    __syncthreads();
    // hoist Z fragments (stable across dt loop)
    bf16x8 zf[2][3];
    #pragma unroll
    for (int kf = 0; kf < 2; ++kf) {
        #pragma unroll
        for (int pl = 0; pl < 3; ++pl)
            zf[kf][pl] = *(const bf16x8*)(&zS[pl][(wv * 16 + fr) * 72 + kf * 32 + fq * 8]);
    }
    // phase 2: out = Z @ w2^T + b2, N=300 in 5 chunks of 64
    for (int dt = 0; dt < 5; ++dt) {
        #pragma unroll
        for (int pl = 0; pl < 3; ++pl) {
            const uint4* g2 = (const uint4*)(w2p + (size_t)pl * 20480 + (size_t)(dt * 64 + ar) * 64 + cs);
            *(uint4*)(&wS[pl][ar * 72 + cs]) = g2[0];
            *(uint4*)(&wS[pl][ar * 72 + cs + 8]) = g2[1];
        }
        __syncthreads();
        f32x4 acc[4] = {};
        #pragma unroll
        for (int nf = 0; nf < 4; ++nf) {
            #pragma unroll
            for (int kf = 0; kf < 2; ++kf) {
                bf16x8 b1f = *(const bf16x8*)(&wS[0][(nf * 16 + fr) * 72 + kf * 32 + fq * 8]);
                bf16x8 b2f = *(const bf16x8*)(&wS[1][(nf * 16 + fr) * 72 + kf * 32 + fq * 8]);
                bf16x8 b3f = *(const bf16x8*)(&wS[2][(nf * 16 + fr) * 72 + kf * 32 + fq * 8]);
                acc[nf] = mfma6(zf[kf][0], zf[kf][1], zf[kf][2], b1f, b2f, b3f, acc[nf]);
            }
        }
        #pragma unroll
        for (int nf = 0; nf < 4; ++nf) {
            const int col = dt * 64 + nf * 16 + fr;
            if (col < DD) {
                float bb = ld1(b2, col, md);
                #pragma unroll
                for (int r = 0; r < 4; ++r) {
                    long long row = gbase + m0 + wv * 16 + fq * 4 + r;
                    float o = acc[nf][r] + bb;
                    if (md) ((float*)out)[row * DD + col] = o;
                    else    ((unsigned short*)out)[row * DD + col] = f2bf(o);
                }
            }
        }
        __syncthreads();
    }
}

// ---------------------------------------------------------------------------
extern "C" void kernel_launch(void* const* d_in, const int* in_sizes, int n_in,
                              void* d_out, int out_size, void* d_ws, size_t ws_size,
                              hipStream_t stream)
{
    const void* inp  = d_in[0];
    const void* h0   = d_in[1];
    const void* c0   = d_in[2];
    const void* wih0 = d_in[3];
    const void* whh0 = d_in[4];
    const void* bih0 = d_in[5];
    const void* bhh0 = d_in[6];
    const void* wih1 = d_in[7];
    const void* whh1 = d_in[8];
    const void* bih1 = d_in[9];
    const void* bhh1 = d_in[10];
    const void* wih2 = d_in[11];
    const void* whh2 = d_in[12];
    const void* bih2 = d_in[13];
    const void* bhh2 = d_in[14];
    const void* w1   = d_in[15];
    const void* b1   = d_in[16];
    const void* w2   = d_in[17];
    const void* b2   = d_in[18];

    int* mode = (int*)d_ws;
    float* wsf = (float*)d_ws;
    float* hstate = wsf + 16;                          // [3,256,64]
    float* cstate = hstate + 3 * BB * HH;
    float* xp  = cstate + 3 * BB * HH;                 // [TC*256, 256]
    float* hs  = xp + (size_t)TC * BB * XP;            // [TC*256, 64] (reused per layer)
    unsigned short* w0s = (unsigned short*)(hs + (size_t)TC * BB * HH);
    unsigned short* w1s = w0s + (size_t)3 * 81920;     // [3][256*320]
    unsigned short* w2s = w1s + (size_t)3 * 16384;     // [3][256*64]
    unsigned short* h1s = w2s + (size_t)3 * 16384;     // [3][256*64]
    unsigned short* h2s = h1s + (size_t)3 * 4096;      // [3][64*64]
                                                       // h2s: [3][320*64]

    detect_kernel<<<1, 64, 0, stream>>>(inp, mode);
    init_state<<<192, 256, 0, stream>>>(h0, c0, hstate, cstate, mode);
    split_w<<<320, 256, 0, stream>>>(wih0, w0s, 256, 300, 256, 320, mode);
    split_w<<<64, 256, 0, stream>>>(wih1, w1s, 256, 64, 256, 64, mode);
    split_w<<<64, 256, 0, stream>>>(wih2, w2s, 256, 64, 256, 64, mode);
    split_w<<<16, 256, 0, stream>>>(w1, h1s, 64, 64, 64, 64, mode);
    split_w<<<80, 256, 0, stream>>>(w2, h2s, 300, 64, 320, 64, mode);

    for (int c = 0; c < NC; ++c) {
        proj0_chunk<<<dim3(TC * BB / 64), 256, 0, stream>>>(
            inp, w0s, bih0, bhh0, xp, mode, c);
        scan_chunk<<<BB, 128, 0, stream>>>(
            xp, hs, whh0, hstate, cstate, mode);
        projh_chunk<<<dim3(TC * BB / 64), 256, 0, stream>>>(
            hs, w1s, bih1, bhh1, xp, mode);
        scan_chunk<<<BB, 128, 0, stream>>>(
            xp, hs, whh1, hstate + BB * HH, cstate + BB * HH, mode);
        projh_chunk<<<dim3(TC * BB / 64), 256, 0, stream>>>(
            hs, w2s, bih2, bhh2, xp, mode);
        scan_chunk<<<BB, 128, 0, stream>>>(
            xp, hs, whh2, hstate + 2 * BB * HH, cstate + 2 * BB * HH, mode);
        head_chunk<<<TC * BB / 64, 256, 0, stream>>>(
            hs, h1s, b1, h2s, b2, d_out, mode, c);
    }
    final_state<<<192, 256, 0, stream>>>(hstate, cstate, d_out, mode);
}